// Round 1
// baseline (305.987 us; speedup 1.0000x reference)
//
#include <hip/hip_runtime.h>

typedef float v2f __attribute__((ext_vector_type(2)));

#define D_MODEL 1024
#define D_STATE 64
#define CHUNK   256
#define TILE_T  64   // timesteps staged in LDS per refill (32 KB total)

// One thread owns one d-column of one (b,chunk) scan: h[64] states in VGPRs.
// grid = 64 (b,c) x 4 d-quarters = 256 blocks of 256 threads -> 1 block/CU.
__global__ __launch_bounds__(256, 1)
void YvParallelScan_kernel(const float* __restrict__ u,
                           const float* __restrict__ B,
                           const float* __restrict__ C,
                           const float* __restrict__ A_log,
                           float* __restrict__ out) {
    __shared__ float4 sB4[TILE_T * 16];   // [tl][g] g = group of 4 n
    __shared__ float4 sC4[TILE_T * 16];

    const int bc = blockIdx.x >> 2;            // 0..63  (b*16 + c)
    const int dq = blockIdx.x & 3;             // d-quarter
    const int d  = dq * 256 + threadIdx.x;     // 0..1023
    const int rowbase = bc * CHUNK;            // == b*4096 + c*256

    // A = -exp(A_log[:, d]); keep as 32 float2 pairs. h starts at 0.
    v2f a2[32], h2[32];
#pragma unroll
    for (int k = 0; k < 32; ++k) {
        float a0 = A_log[(size_t)(2 * k)     * D_MODEL + d];
        float a1 = A_log[(size_t)(2 * k + 1) * D_MODEL + d];
        v2f av; av.x = -__expf(a0); av.y = -__expf(a1);
        a2[k] = av;
        v2f z; z.x = 0.f; z.y = 0.f;
        h2[k] = z;
    }

    const float*  uptr = u   + (size_t)rowbase * D_MODEL + d;
    float*        optr = out + (size_t)rowbase * D_MODEL + d;
    const float4* Bg   = (const float4*)(B + (size_t)rowbase * D_STATE);
    const float4* Cg   = (const float4*)(C + (size_t)rowbase * D_STATE);

    // software prefetch of x two timesteps ahead
    float xa = uptr[0];
    float xb = uptr[D_MODEL];

    for (int ti = 0; ti < CHUNK / TILE_T; ++ti) {
        __syncthreads();
        // refill tile: 1024 float4 each for B and C, coalesced
#pragma unroll
        for (int k = 0; k < 4; ++k) {
            int flat = threadIdx.x + k * 256;
            sB4[flat] = Bg[ti * (TILE_T * 16) + flat];
            sC4[flat] = Cg[ti * (TILE_T * 16) + flat];
        }
        __syncthreads();

#pragma unroll 2
        for (int tl = 0; tl < TILE_T; ++tl) {
            const int t  = ti * TILE_T + tl;
            const int tp = (t + 2 < CHUNK) ? (t + 2) : (CHUNK - 1);
            float xn = uptr[(size_t)tp * D_MODEL];   // issue early, use in 2 iters

            v2f xx;   xx.x = xa;  xx.y = xa;
            v2f acc0; acc0.x = 0.f; acc0.y = 0.f;
            v2f acc1; acc1.x = 0.f; acc1.y = 0.f;

#pragma unroll
            for (int g = 0; g < 16; ++g) {
                float4 b4 = sB4[tl * 16 + g];   // broadcast ds_read_b128
                float4 c4 = sC4[tl * 16 + g];
                v2f b01; b01.x = b4.x; b01.y = b4.y;
                v2f b23; b23.x = b4.z; b23.y = b4.w;
                v2f c01; c01.x = c4.x; c01.y = c4.y;
                v2f c23; c23.x = c4.z; c23.y = c4.w;

                h2[2 * g]     = a2[2 * g]     * h2[2 * g]     + b01 * xx;
                h2[2 * g + 1] = a2[2 * g + 1] * h2[2 * g + 1] + b23 * xx;
                acc0 += c01 * h2[2 * g];
                acc1 += c23 * h2[2 * g + 1];
            }

            optr[(size_t)t * D_MODEL] = (acc0.x + acc0.y) + (acc1.x + acc1.y);
            xa = xb;
            xb = xn;
        }
    }
}

extern "C" void kernel_launch(void* const* d_in, const int* in_sizes, int n_in,
                              void* d_out, int out_size, void* d_ws, size_t ws_size,
                              hipStream_t stream) {
    const float* u     = (const float*)d_in[0];
    // d_in[1] = delta, unused by the reference forward
    const float* B     = (const float*)d_in[2];
    const float* C     = (const float*)d_in[3];
    const float* A_log = (const float*)d_in[4];
    float* out = (float*)d_out;

    YvParallelScan_kernel<<<256, 256, 0, stream>>>(u, B, C, A_log, out);
}